// Round 26
// baseline (179.586 us; speedup 1.0000x reference)
//
#include <hip/hip_runtime.h>
#include <vector>
#include <cmath>
#include <cstring>

#define PI_D 3.14159265358979323846

typedef unsigned short ushort_t;
typedef __attribute__((ext_vector_type(8))) short bf16x8;
typedef __attribute__((ext_vector_type(4))) float f32x4;

// ---------------- constant blob layout ----------------
#define CF_TRIG_F 0            // 3*32*2 = 192 floats
#define CF_EVP_F  192          // 3*192*256 = 147456 floats
#define CF_FLOATS 147648
// Kt frag-linear per scale: offset = 98304*((1<<s)-1) ushorts
#define CU_USHORTS 688128
#define CONST_BYTES (CF_FLOATS*4 + CU_USHORTS*2)      // 1,966,848 B

// ---------------- workspace layout (float offsets); ws ~268 MB ----------
#define OFF_XCT   0            // 168*768 = 129024
#define OFF_MEANS 129024       // 256
#define OFF_STD   129280       // 256
#define OFF_OUT1  129536       // 3*168*256 = 129024 -> ends 258560
#define OFF_XP1P  258560       // 225792 double2 = 903168 floats -> ends 1161728
#define OFF_PART  1161728      // 3*32*168*256 = 4128768 -> ends 5290496
#define OFF_AHI   5290496      // 3*10752*256 us = 4128768 floats -> ends 9419264
#define OFF_ALO   9419264      // same -> ends 13548032
#define OFF_FB2   13548032     // 3*16384*256*2 us = 12582912 floats -> ends 26130944
#define OFF_YF    26130944     // 28901376 us = 14450688 floats -> ends 40581632
#define OFF_CFALL 40581632     // fallback const blob (491712) -> 41073344 fl = 164 MB

static const int L_S[3] = {192, 384, 768};

// ---------------- host bf16 helpers ----------------
static inline unsigned short h_f2b(float v) {
  unsigned int u; memcpy(&u, &v, 4);
  unsigned int r = (u + 0x7FFF + ((u >> 16) & 1)) >> 16;
  return (unsigned short)r;
}
static inline float h_b2f(unsigned short h) {
  unsigned int u = (unsigned int)h << 16; float f; memcpy(&f, &u, 4); return f;
}

// ---------------- host-side constant generation (static init) ----------------
static unsigned char g_consts[CONST_BYTES];

static void compute_consts_host(unsigned char* blob) {
  float* outf = (float*)blob;
  ushort_t* outu = (ushort_t*)(blob + CF_FLOATS * 4);
  const int N = 256;
  for (int s = 0; s < 3; ++s) {
    const int L = L_S[s];
    const int m = 1 << s;
    const double dt = 1.0 / 192.0 / (double)m;

    for (int k = 0; k < 32; ++k) {
      double th = 2.0 * PI_D * (double)k * 191.0 / (double)L;
      outf[CF_TRIG_F + s * 64 + 2 * k]     = (float)cos(th);
      outf[CF_TRIG_F + s * 64 + 2 * k + 1] = (float)sin(th);
    }
    for (int r = 0; r < 192; ++r) {
      int irow = L - 192 + r;
      double x = 1.0 - 2.0 * ((double)irow * dt);
      float* dst = outf + CF_EVP_F + ((size_t)s * 192 + r) * 256;
      double pm1 = 1.0, pc = x;
      dst[0] = 1.0f; dst[1] = (float)x;
      for (int n = 1; n < N - 1; ++n) {
        double pn = ((2.0 * n + 1.0) * x * pc - (double)n * pm1) / (double)(n + 1);
        pm1 = pc; pc = pn;
        dst[n + 1] = (float)pn;
      }
    }
    const int W = N + 257;
    std::vector<double> G((size_t)N * W);
    for (int i = 0; i < N; ++i) {
      double R = 2.0 * i + 1.0;
      for (int j = 0; j < N; ++j) {
        double a = (i < j) ? -R : ((((i - j + 1) & 1) ? -R : R));
        G[(size_t)i * W + j]     = (i == j ? 1.0 : 0.0) - 0.5 * dt * a;
        G[(size_t)i * W + N + j] = (i == j ? 1.0 : 0.0) + 0.5 * dt * a;
      }
      G[(size_t)i * W + N + 256] = dt * (((i & 1) ? -R : R));
    }
    for (int k = 0; k < N; ++k) {
      int piv = k; double best = fabs(G[(size_t)k * W + k]);
      for (int r = k + 1; r < N; ++r) {
        double v = fabs(G[(size_t)r * W + k]);
        if (v > best) { best = v; piv = r; }
      }
      if (piv != k)
        for (int c = k; c < W; ++c) std::swap(G[(size_t)k * W + c], G[(size_t)piv * W + c]);
      double inv = 1.0 / G[(size_t)k * W + k];
      for (int r = k + 1; r < N; ++r) {
        double f = G[(size_t)r * W + k] * inv;
        if (f != 0.0) {
          double* Rr = &G[(size_t)r * W];
          const double* Rk = &G[(size_t)k * W];
          for (int c = k; c < W; ++c) Rr[c] -= f * Rk[c];
        }
      }
    }
    std::vector<double> X((size_t)N * 257);
    for (int k = N - 1; k >= 0; --k) {
      double inv = 1.0 / G[(size_t)k * W + k];
      const double* Rk = &G[(size_t)k * W];
      for (int c = 0; c < 257; ++c) {
        double v = Rk[N + c];
        for (int j = k + 1; j < N; ++j) v -= Rk[j] * X[(size_t)j * 257 + c];
        X[(size_t)k * 257 + c] = v * inv;
      }
    }
    std::vector<double> Ad((size_t)N * N), kvec(N), knew(N);
    for (int i = 0; i < N; ++i)
      for (int j = 0; j < N; ++j)
        Ad[(size_t)i * N + j] = (double)(float)X[(size_t)i * 257 + j];
    for (int i = 0; i < N; ++i) kvec[i] = (double)(float)X[(size_t)i * 257 + 256];

    ushort_t* fkt = outu + 98304 * ((1 << s) - 1);
    for (int d = 0; d < L; ++d) {
      if (d > 0) {
        for (int i = 0; i < N; ++i) {
          const double* row = &Ad[(size_t)i * N];
          double acc = 0.0;
          for (int j = 0; j < N; ++j) acc += row[j] * kvec[j];
          knew[i] = acc;
        }
        kvec.swap(knew);
      }
      for (int n = 0; n < N; ++n) {
        float kv = (float)kvec[n];
        unsigned short hi = h_f2b(kv);
        unsigned short lo = h_f2b(kv - h_b2f(hi));
        size_t base = ((size_t)((d >> 5) * 16 + (n >> 4)) * 2) * 512
                    + (size_t)((d & 31) >> 3) * 128 + (size_t)(n & 15) * 8 + (d & 7);
        fkt[base]       = hi;
        fkt[base + 512] = lo;
      }
    }
  }
}

static bool  g_dev_ok  = false;
static void* g_dev_ptr = nullptr;

namespace {
struct ConstInit {
  ConstInit() {
    compute_consts_host(g_consts);
    void* p = nullptr;
    if (hipMalloc(&p, CONST_BYTES) == hipSuccess && p != nullptr) {
      if (hipMemcpy(p, g_consts, CONST_BYTES, hipMemcpyHostToDevice) == hipSuccess) {
        g_dev_ptr = p;
        g_dev_ok  = true;
      } else {
        (void)hipFree(p);
      }
    }
    (void)hipHostRegister((void*)g_consts, sizeof(g_consts), hipHostRegisterDefault);
  }
};
static ConstInit g_const_init;
}

// ---------------- device helpers ----------------
__device__ inline unsigned short f2b(float v) {
  unsigned int u = __float_as_uint(v);
  unsigned int r = (u + 0x7FFF + ((u >> 16) & 1)) >> 16;
  return (unsigned short)r;
}
__device__ inline float b2f(unsigned short h) {
  return __uint_as_float((unsigned int)h << 16);
}
__device__ inline unsigned int pack2(float a, float b) {
  return (unsigned int)f2b(a) | ((unsigned int)f2b(b) << 16);
}

__device__ inline float blockReduceSum(float v) {
  __shared__ float sm[4];
  #pragma unroll
  for (int off = 32; off > 0; off >>= 1) v += __shfl_down(v, off);
  int wid = threadIdx.x >> 6, lane = threadIdx.x & 63;
  if (lane == 0) sm[wid] = v;
  __syncthreads();
  if (threadIdx.x == 0) sm[0] = sm[0] + sm[1] + sm[2] + sm[3];
  __syncthreads();
  float r = sm[0];
  __syncthreads();
  return r;
}

// instance norm over SEQ, write transposed xcT[bj][t]
__global__ __launch_bounds__(256) void norm_kernel(
    const float* __restrict__ x_enc, const float* __restrict__ aw,
    const float* __restrict__ ab, float* __restrict__ xcT,
    float* __restrict__ means, float* __restrict__ stdev) {
  int bj = blockIdx.x; int b = bj / 21, j = bj % 21;
  const float* xp = x_enc + (size_t)b * 768 * 21 + j;
  int tid = threadIdx.x;
  float lv[3]; float s = 0.f;
  #pragma unroll
  for (int i = 0; i < 3; ++i) { lv[i] = xp[(size_t)(tid + 256 * i) * 21]; s += lv[i]; }
  float tot = blockReduceSum(s);
  float mean = tot * (1.0f / 768.0f);
  float v = 0.f;
  #pragma unroll
  for (int i = 0; i < 3; ++i) { float d = lv[i] - mean; v += d * d; }
  float totv = blockReduceSum(v);
  float sd = sqrtf(totv * (1.0f / 768.0f) + 1e-5f);
  if (tid == 0) { means[bj] = mean; stdev[bj] = sd; }
  float wj = aw[j], bjv = ab[j];
  #pragma unroll
  for (int i = 0; i < 3; ++i)
    xcT[(size_t)bj * 768 + tid + 256 * i] = ((lv[i] - mean) / sd) * wj + bjv;
}

// ---- batched chunked prefix-DFT (f32 rotators, f64 anchors + accum).
__global__ __launch_bounds__(256) void xp1_kernel(
    const float* __restrict__ xcT, double2* __restrict__ P) {
  int tid = blockIdx.x * 256 + threadIdx.x;
  if (tid >= 5376 * 42) return;
  int nk = tid % 5376, cg = tid / 5376;
  int scale = (cg < 6) ? 0 : (cg < 18 ? 1 : 2);
  int c = cg - 6 * ((1 << scale) - 1);
  int L = 192 << scale;
  int bj = nk >> 5, k = nk & 31;
  const float* x = xcT + (size_t)bj * 768 + (768 - L);
  int u0 = c * 32;
  double ang = -2.0 * PI_D * (double)((k * u0) % L) / (double)L;
  float re = (float)cos(ang), im = (float)sin(ang);
  double wang = -2.0 * PI_D * (double)k / (double)L;
  float cw = (float)cos(wang), sw = (float)sin(wang);
  double sre = 0.0, sim = 0.0;
  #pragma unroll 8
  for (int j = 0; j < 32; ++j) {
    float xv = x[u0 + j];
    sre += (double)(xv * re); sim += (double)(xv * im);
    float nr = re * cw - im * sw, ni = re * sw + im * cw;
    re = nr; im = ni;
  }
  P[(size_t)cg * 5376 + nk] = make_double2(sre, sim);
}

// Phase 2 (batched): scan + emit Y frag-linear bf16 hi/lo per scale.
__global__ __launch_bounds__(256) void xp2_kernel(
    const float* __restrict__ xcT, const double2* __restrict__ P,
    ushort_t* __restrict__ YF) {
  int tid = blockIdx.x * 256 + threadIdx.x;
  if (tid >= 5376 * 42) return;
  int nk = tid % 5376, cg = tid / 5376;
  int scale = (cg < 6) ? 0 : (cg < 18 ? 1 : 2);
  int cbase = 6 * ((1 << scale) - 1);
  int c = cg - cbase;
  int L = 192 << scale;
  ushort_t* FA = YF + (size_t)4128768 * ((1 << scale) - 1);
  int bj = nk >> 5, k = nk & 31;
  const float* x = xcT + (size_t)bj * 768 + (768 - L);
  double bre = 0.0, bim = 0.0;
  for (int cc = cbase; cc < cg; ++cc) {
    double2 p = P[(size_t)cc * 5376 + nk];
    bre += p.x; bim += p.y;
  }
  int u0 = c * 32;
  double ang = -2.0 * PI_D * (double)((k * u0) % L) / (double)L;
  float ure = (float)cos(ang), uim = (float)sin(ang);
  double wang = -2.0 * PI_D * (double)k / (double)L;
  float cw = (float)cos(wang), sw = (float)sin(wang);
  int d0 = L - 1 - u0;
  double angd = -2.0 * PI_D * (double)((k * d0) % L) / (double)L;
  float dre = (float)cos(angd), dim = (float)sin(angd);

  float vre_buf[32], vim_buf[32];
  #pragma unroll
  for (int j = 0; j < 32; ++j) {
    float xv = x[u0 + j];
    bre += (double)(xv * ure); bim += (double)(xv * uim);
    float brf = (float)bre, bif = (float)bim;
    int m = 31 - j;
    vre_buf[m] = dre * brf - dim * bif;
    vim_buf[m] = dre * bif + dim * brf;
    float t1 = ure * cw - uim * sw, t2 = ure * sw + uim * cw;
    ure = t1; uim = t2;                  // *= e^{-i w}
    float t3 = dre * cw + dim * sw, t4 = dim * cw - dre * sw;
    dre = t3; dim = t4;                  // *= e^{+i w}
  }

  int nK0 = L >> 5;
  int K0 = (d0 - 31) >> 5;
  int rre = bj * 64 + k * 2;
  int rim = rre + 1;
  size_t baseRe = (((size_t)(rre >> 4) * nK0 + K0) * 2) * 512 + (size_t)(rre & 15) * 8;
  size_t baseIm = (((size_t)(rim >> 4) * nK0 + K0) * 2) * 512 + (size_t)(rim & 15) * 8;
  #pragma unroll
  for (int q = 0; q < 4; ++q) {
    float f0 = vre_buf[q*8+0], f1 = vre_buf[q*8+1], f2 = vre_buf[q*8+2], f3 = vre_buf[q*8+3];
    float f4 = vre_buf[q*8+4], f5 = vre_buf[q*8+5], f6 = vre_buf[q*8+6], f7 = vre_buf[q*8+7];
    uint4 vh = make_uint4(pack2(f0,f1), pack2(f2,f3), pack2(f4,f5), pack2(f6,f7));
    uint4 vl = make_uint4(pack2(f0-b2f(f2b(f0)), f1-b2f(f2b(f1))),
                          pack2(f2-b2f(f2b(f2)), f3-b2f(f2b(f3))),
                          pack2(f4-b2f(f2b(f4)), f5-b2f(f2b(f5))),
                          pack2(f6-b2f(f2b(f6)), f7-b2f(f2b(f7))));
    *(uint4*)(FA + baseRe + q*128)       = vh;
    *(uint4*)(FA + baseRe + 512 + q*128) = vl;
  }
  #pragma unroll
  for (int q = 0; q < 4; ++q) {
    float f0 = vim_buf[q*8+0], f1 = vim_buf[q*8+1], f2 = vim_buf[q*8+2], f3 = vim_buf[q*8+3];
    float f4 = vim_buf[q*8+4], f5 = vim_buf[q*8+5], f6 = vim_buf[q*8+6], f7 = vim_buf[q*8+7];
    uint4 vh = make_uint4(pack2(f0,f1), pack2(f2,f3), pack2(f4,f5), pack2(f6,f7));
    uint4 vl = make_uint4(pack2(f0-b2f(f2b(f0)), f1-b2f(f2b(f1))),
                          pack2(f2-b2f(f2b(f2)), f3-b2f(f2b(f3))),
                          pack2(f4-b2f(f2b(f4)), f5-b2f(f2b(f5))),
                          pack2(f6-b2f(f2b(f6)), f7-b2f(f2b(f7))));
    *(uint4*)(FA + baseIm + q*128)       = vh;
    *(uint4*)(FA + baseIm + 512 + q*128) = vl;
  }
}

// FUSED wb + gemm1 v9: blocks [0,384) wb; blocks [384,720) gemm1 with B
// (Kt) double-buffer staged in LDS via global_load_lds (async DMA; no VGPR
// round-trip; single barrier per K0 drains in-flight stage).
__global__ __launch_bounds__(768, 2) void gemm1_wb(
    const ushort_t* __restrict__ YF, const ushort_t* __restrict__ KTall,
    ushort_t* __restrict__ AHI, ushort_t* __restrict__ ALO,
    const float* __restrict__ wrS_all, const float* __restrict__ wiS_all,
    const float* __restrict__ trig_all, ushort_t* __restrict__ FB2_all) {
  __shared__ ushort_t Bs[2][16384];   // 2 x 32 frags x 512 us = 64 KB

  if (blockIdx.x < 384) {
    // ---- wb path (512 active threads; LDS unused) ----
    if (threadIdx.x >= 512) return;
    int wbid = blockIdx.x;
    int of  = wbid & 15;
    int nsb = (wbid >> 4) & 7;
    int s   = wbid >> 7;
    const float* wrS = wrS_all + (size_t)s * 256 * 256 * 32;
    const float* wiS = wiS_all + (size_t)s * 256 * 256 * 32;
    const float* trig = trig_all + s * 64;
    ushort_t* FB2 = FB2_all + (size_t)s * 8388608;
    int L = 192 << s;
    int t = threadIdx.x;
    int lgk = t >> 7;
    int e   = t & 7;
    int om  = (t >> 3) & 15;
    int nstate = nsb * 32 + lgk * 8 + e;
    int o = of * 16 + om;
    const float* wrp = wrS + ((size_t)nstate * 256 + o) * 32;
    const float* wip = wiS + ((size_t)nstate * 256 + o) * 32;
    float invL = 1.0f / (float)L;
    #pragma unroll 4
    for (int k = 0; k < 32; ++k) {
      float ck = trig[2 * k], sk = trig[2 * k + 1];
      float fk = (k == 0 ? 1.0f : 2.0f) * invL;
      float wr = wrp[k], wi = wip[k];
      float vre = fk * (wr * ck - wi * sk);
      float vim = fk * (-wi * ck - wr * sk);
      int qre = (k * 2) * 8 + nsb;
      size_t bre = ((size_t)(qre * 16 + of) * 2) * 512 + t;
      size_t bim = ((size_t)((qre + 8) * 16 + of) * 2) * 512 + t;
      unsigned short hre = f2b(vre), him = f2b(vim);
      FB2[bre]       = hre;
      FB2[bre + 512] = f2b(vre - b2f(hre));
      FB2[bim]       = him;
      FB2[bim + 512] = f2b(vim - b2f(him));
    }
    return;
  }

  // ---- gemm1 path v9: 112x3 logical grid, 12 waves, 2 strips per mh,
  //      B staged in LDS (double buffer) via global_load_lds ----
  const int gb = blockIdx.x - 384;
  const int s = gb / 112;
  const int bx = gb % 112;
  const int K = 192 << s;
  const ushort_t* FA = YF + (size_t)4128768 * ((1 << s) - 1);
  const ushort_t* FB = KTall + (size_t)98304 * ((1 << s) - 1);
  ushort_t* Chi = AHI + (size_t)2752512 * s;
  ushort_t* Clo = ALO + (size_t)2752512 * s;

  const int wave = threadIdx.x >> 6;
  const int lane = threadIdx.x & 63;
  const int li = lane & 15, lg = lane >> 4;
  const int mh = wave >> 2;             // 0..2
  const int nw = wave & 3;              // 0..3 col quarter
  const int bn = nw * 64;
  const int nK0 = K >> 5;               // 6, 12, 24
  const int strip = bx * 6 + mh * 2;    // wave covers strip, strip+1
  const int nf0 = nw * 4;

  // stage all 32 B-frags (16 nf x hi/lo) of K-block K0_ into Bs[CUR]
  #define STAGE_B(CUR, K0_) {                                                 \
    for (int f = wave; f < 32; f += 12) {                                     \
      const ushort_t* gsrc = FB                                               \
          + ((size_t)((K0_) * 16 + (f >> 1)) * 2 + (f & 1)) * 512 + lane * 8; \
      __builtin_amdgcn_global_load_lds(                                       \
          (const __attribute__((address_space(1))) void*)gsrc,                \
          (__attribute__((address_space(3))) void*)&Bs[CUR][f * 512],         \
          16, 0, 0);                                                          \
    } }

  bf16x8 aH[2], aL[2];
  f32x4 acc[2][4] = {};

  STAGE_B(0, 0);
  __syncthreads();

  int cur = 0;
  for (int K0 = 0; K0 < nK0; ++K0) {
    // A register loads for this K0 (2 strips)
    #pragma unroll
    for (int st = 0; st < 2; ++st) {
      size_t fa = ((size_t)((strip + st) * nK0 + K0) * 2) * 512 + lane * 8;
      aH[st] = *(const bf16x8*)(FA + fa);
      aL[st] = *(const bf16x8*)(FA + fa + 512);
    }
    // stage next B while computing current
    if (K0 + 1 < nK0) STAGE_B(cur ^ 1, K0 + 1);
    // compute from Bs[cur]
    #pragma unroll
    for (int nf = 0; nf < 4; ++nf) {
      bf16x8 bh = *(const bf16x8*)&Bs[cur][((nf0 + nf) * 2 + 0) * 512 + lane * 8];
      bf16x8 bl = *(const bf16x8*)&Bs[cur][((nf0 + nf) * 2 + 1) * 512 + lane * 8];
      #pragma unroll
      for (int st = 0; st < 2; ++st) {
        acc[st][nf] = __builtin_amdgcn_mfma_f32_16x16x32_bf16(aH[st], bh, acc[st][nf], 0, 0, 0);
        acc[st][nf] = __builtin_amdgcn_mfma_f32_16x16x32_bf16(aH[st], bl, acc[st][nf], 0, 0, 0);
        acc[st][nf] = __builtin_amdgcn_mfma_f32_16x16x32_bf16(aL[st], bh, acc[st][nf], 0, 0, 0);
      }
    }
    __syncthreads();   // drains in-flight stage; protects buffer reuse
    cur ^= 1;
  }
  #undef STAGE_B

  #pragma unroll
  for (int st = 0; st < 2; ++st) {
    #pragma unroll
    for (int r = 0; r < 4; ++r) {
      int row = (strip + st) * 16 + lg * 4 + r;
      #pragma unroll
      for (int nf = 0; nf < 4; ++nf) {
        int col = bn + nf * 16 + li;
        float v = acc[st][nf][r];
        unsigned short hi = f2b(v);
        Chi[(size_t)row * 256 + col] = hi;
        Clo[(size_t)row * 256 + col] = f2b(v - b2f(hi));
      }
    }
  }
}

// GEMM2 (batched): grid (4 nx, 3 my, 96 = scale*32+z), 256 thr.
__global__ __launch_bounds__(256) void gemm2_mfma(
    const ushort_t* __restrict__ AHI, const ushort_t* __restrict__ ALO,
    const ushort_t* __restrict__ FB2_all, float* __restrict__ PART) {
  const int zz = blockIdx.z;
  const int s = zz >> 5;
  const int z = zz & 31;
  const ushort_t* Ahi = AHI + (size_t)2752512 * s;
  const ushort_t* Alo = ALO + (size_t)2752512 * s;
  const ushort_t* FB2 = FB2_all + (size_t)s * 8388608;
  float* C = PART + (size_t)s * 1376256 + (size_t)z * 43008;

  const int wave = threadIdx.x >> 6;
  const int lane = threadIdx.x & 63;
  const int li = lane & 15, lg = lane >> 4;
  const int bm = blockIdx.y * 64;
  const int bn = blockIdx.x * 64;
  const int nf0 = blockIdx.x * 4;
  const int ks = z * 512;

  const int rowA = bm + wave * 16 + li;
  const bool aok = (rowA < 168);
  const size_t aoff = (size_t)(aok ? rowA : 0) * 16384;

  bf16x8 aH0, aL0, bH0[4], bL0[4];
  bf16x8 aH1, aL1, bH1[4], bL1[4];
  f32x4 acc[4] = {};

  #define G2_LOAD(AH, AL, BH, BL, KC_) {                                   \
    int kc_ = (KC_) + lg * 8;                                              \
    if (aok) { AH = *(const bf16x8*)(Ahi + aoff + kc_);                    \
               AL = *(const bf16x8*)(Alo + aoff + kc_); }                  \
    else     { AH = (bf16x8)(short)0; AL = (bf16x8)(short)0; }             \
    int q_ = (KC_) >> 5;                                                   \
    _Pragma("unroll")                                                      \
    for (int nf = 0; nf < 4; ++nf) {                                       \
      size_t fb = ((size_t)(q_ * 16 + nf0 + nf) * 2) * 512 + lane * 8;     \
      BH[nf] = *(const bf16x8*)(FB2 + fb);                                 \
      BL[nf] = *(const bf16x8*)(FB2 + fb + 512);                           \
    } }

  #define G2_MFMA(AH, AL, BH, BL) {                                        \
    _Pragma("unroll")                                                      \
    for (int nf = 0; nf < 4; ++nf) {                                       \
      acc[nf] = __builtin_amdgcn_mfma_f32_16x16x32_bf16(AH, BH[nf], acc[nf], 0, 0, 0); \
      acc[nf] = __builtin_amdgcn_mfma_f32_16x16x32_bf16(AH, BL[nf], acc[nf], 0, 0, 0); \
      acc[nf] = __builtin_amdgcn_mfma_f32_16x16x32_bf16(AL, BH[nf], acc[nf], 0, 0, 0); \
    } }

  G2_LOAD(aH0, aL0, bH0, bL0, ks);
  for (int k0 = ks; k0 < ks + 512; k0 += 64) {
    G2_LOAD(aH1, aL1, bH1, bL1, k0 + 32);
    G2_MFMA(aH0, aL0, bH0, bL0);
    if (k0 + 64 < ks + 512) G2_LOAD(aH0, aL0, bH0, bL0, k0 + 64);
    G2_MFMA(aH1, aL1, bH1, bL1);
  }
  #undef G2_LOAD
  #undef G2_MFMA

  #pragma unroll
  for (int r = 0; r < 4; ++r) {
    int row = bm + wave * 16 + lg * 4 + r;
    if (row < 168) {
      #pragma unroll
      for (int nf = 0; nf < 4; ++nf) {
        int col = bn + nf * 16 + li;
        C[(size_t)row * 256 + col] = acc[nf][r];
      }
    }
  }
}

// reduce (batched): grid (168, 3)
__global__ __launch_bounds__(256) void reduce_kernel(
    const float* __restrict__ PART, float* __restrict__ OUT1) {
  int s = blockIdx.y;
  int e = blockIdx.x * 256 + threadIdx.x;   // 43008 exact
  const float* part = PART + (size_t)s * 1376256;
  float sum = 0.f;
  for (int c = 0; c < 32; ++c) sum += part[(size_t)c * 43008 + e];
  OUT1[(size_t)s * 43008 + e] = sum;
}

// out[b][p][j] = ((sum_s mlpw_s*(out1_s[bj].evp_s[p]) + mlpb) - ab[j])/(aw[j]+1e-10)*sd + mean
__global__ __launch_bounds__(256) void final_kernel(
    const float* __restrict__ out1, const float* __restrict__ evp,
    const float* __restrict__ means, const float* __restrict__ stdev,
    const float* __restrict__ aw, const float* __restrict__ ab,
    const float* __restrict__ mlp_w, const float* __restrict__ mlp_b,
    float* __restrict__ out) {
  int tid = blockIdx.x * 256 + threadIdx.x;   // 8*192*21 = 32256 exact
  int j = tid % 21; int bp = tid / 21; int p = bp % 192; int b = bp / 192;
  int bj = b * 21 + j;
  float acc = mlp_b[0];
  #pragma unroll
  for (int s = 0; s < 3; ++s) {
    const float* o1 = out1 + ((size_t)s * 168 + bj) * 256;
    const float* ev = evp + ((size_t)s * 192 + p) * 256;
    float d = 0.f;
    #pragma unroll 4
    for (int n = 0; n < 256; ++n) d = fmaf(o1[n], ev[n], d);
    acc = fmaf(mlp_w[s], d, acc);
  }
  float v = (acc - ab[j]) / (aw[j] + 1e-10f);
  out[tid] = v * stdev[bj] + means[bj];
}

// ---------------- launch ----------------
extern "C" void kernel_launch(void* const* d_in, const int* in_sizes, int n_in,
                              void* d_out, int out_size, void* d_ws, size_t ws_size,
                              hipStream_t stream) {
  const float* x_enc   = (const float*)d_in[0];
  const float* aw      = (const float*)d_in[4];
  const float* ab      = (const float*)d_in[5];
  const float* spec_wr = (const float*)d_in[6];
  const float* spec_wi = (const float*)d_in[7];
  const float* mlp_w   = (const float*)d_in[8];
  const float* mlp_b   = (const float*)d_in[9];
  float* wsf = (float*)d_ws;
  float* out = (float*)d_out;

  const unsigned char* cst_base;
  if (g_dev_ok) {
    cst_base = (const unsigned char*)g_dev_ptr;   // uploaded once at dlopen
  } else {
    hipMemcpyAsync(wsf + OFF_CFALL, g_consts, CONST_BYTES,
                   hipMemcpyHostToDevice, stream);
    cst_base = (const unsigned char*)(wsf + OFF_CFALL);
  }
  const float*    cst_f  = (const float*)cst_base;
  const ushort_t* cst_us = (const ushort_t*)(cst_base + CF_FLOATS * 4);

  ushort_t* yf  = (ushort_t*)(wsf + OFF_YF);
  ushort_t* ahi = (ushort_t*)(wsf + OFF_AHI);
  ushort_t* alo = (ushort_t*)(wsf + OFF_ALO);
  ushort_t* fb2 = (ushort_t*)(wsf + OFF_FB2);

  norm_kernel<<<168, 256, 0, stream>>>(x_enc, aw, ab,
      wsf + OFF_XCT, wsf + OFF_MEANS, wsf + OFF_STD);

  // batched over all 3 scales:
  xp1_kernel<<<(5376 * 42 + 255) / 256, 256, 0, stream>>>(
      wsf + OFF_XCT, (double2*)(wsf + OFF_XP1P));
  xp2_kernel<<<(5376 * 42 + 255) / 256, 256, 0, stream>>>(
      wsf + OFF_XCT, (const double2*)(wsf + OFF_XP1P), yf);
  // fused wb (384 blocks) + gemm1 v9 (336 blocks, LDS-staged B)
  gemm1_wb<<<384 + 336, 768, 0, stream>>>(
      yf, cst_us, ahi, alo,
      spec_wr, spec_wi, cst_f + CF_TRIG_F, fb2);
  gemm2_mfma<<<dim3(4, 3, 96), 256, 0, stream>>>(
      ahi, alo, fb2, wsf + OFF_PART);
  reduce_kernel<<<dim3(168, 3), 256, 0, stream>>>(
      wsf + OFF_PART, wsf + OFF_OUT1);

  final_kernel<<<126, 256, 0, stream>>>(
      wsf + OFF_OUT1, cst_f + CF_EVP_F, wsf + OFF_MEANS, wsf + OFF_STD,
      aw, ab, mlp_w, mlp_b, out);
}

// Round 27
// 178.060 us; speedup vs baseline: 1.0086x; 1.0086x over previous
//
#include <hip/hip_runtime.h>
#include <vector>
#include <cmath>
#include <cstring>

#define PI_D 3.14159265358979323846

typedef unsigned short ushort_t;
typedef __attribute__((ext_vector_type(8))) short bf16x8;
typedef __attribute__((ext_vector_type(4))) float f32x4;

// ---------------- constant blob layout ----------------
#define CF_TRIG_F 0            // 3*32*2 = 192 floats
#define CF_EVP_F  192          // 3*192*256 = 147456 floats
#define CF_FLOATS 147648
// Kt frag-linear per scale: offset = 98304*((1<<s)-1) ushorts
#define CU_USHORTS 688128
#define CONST_BYTES (CF_FLOATS*4 + CU_USHORTS*2)      // 1,966,848 B

// ---------------- workspace layout (float offsets); ws ~268 MB ----------
#define OFF_XCT   0            // 168*768 = 129024
#define OFF_MEANS 129024       // 256
#define OFF_STD   129280       // 256
#define OFF_OUT1  129536       // 3*168*256 = 129024 -> ends 258560
#define OFF_XP1P  258560       // 225792 double2 = 903168 floats -> ends 1161728
#define OFF_PART  1161728      // 3*32*168*256 = 4128768 -> ends 5290496
#define OFF_AHI   5290496      // 3*10752*256 us = 4128768 floats -> ends 9419264
#define OFF_ALO   9419264      // same -> ends 13548032
#define OFF_FB2   13548032     // 3*16384*256*2 us = 12582912 floats -> ends 26130944
#define OFF_YF    26130944     // 28901376 us = 14450688 floats -> ends 40581632
#define OFF_CFALL 40581632     // fallback const blob (491712) -> 41073344 fl = 164 MB

static const int L_S[3] = {192, 384, 768};

// ---------------- host bf16 helpers ----------------
static inline unsigned short h_f2b(float v) {
  unsigned int u; memcpy(&u, &v, 4);
  unsigned int r = (u + 0x7FFF + ((u >> 16) & 1)) >> 16;
  return (unsigned short)r;
}
static inline float h_b2f(unsigned short h) {
  unsigned int u = (unsigned int)h << 16; float f; memcpy(&f, &u, 4); return f;
}

// ---------------- host-side constant generation (static init) ----------------
static unsigned char g_consts[CONST_BYTES];

static void compute_consts_host(unsigned char* blob) {
  float* outf = (float*)blob;
  ushort_t* outu = (ushort_t*)(blob + CF_FLOATS * 4);
  const int N = 256;
  for (int s = 0; s < 3; ++s) {
    const int L = L_S[s];
    const int m = 1 << s;
    const double dt = 1.0 / 192.0 / (double)m;

    for (int k = 0; k < 32; ++k) {
      double th = 2.0 * PI_D * (double)k * 191.0 / (double)L;
      outf[CF_TRIG_F + s * 64 + 2 * k]     = (float)cos(th);
      outf[CF_TRIG_F + s * 64 + 2 * k + 1] = (float)sin(th);
    }
    for (int r = 0; r < 192; ++r) {
      int irow = L - 192 + r;
      double x = 1.0 - 2.0 * ((double)irow * dt);
      float* dst = outf + CF_EVP_F + ((size_t)s * 192 + r) * 256;
      double pm1 = 1.0, pc = x;
      dst[0] = 1.0f; dst[1] = (float)x;
      for (int n = 1; n < N - 1; ++n) {
        double pn = ((2.0 * n + 1.0) * x * pc - (double)n * pm1) / (double)(n + 1);
        pm1 = pc; pc = pn;
        dst[n + 1] = (float)pn;
      }
    }
    const int W = N + 257;
    std::vector<double> G((size_t)N * W);
    for (int i = 0; i < N; ++i) {
      double R = 2.0 * i + 1.0;
      for (int j = 0; j < N; ++j) {
        double a = (i < j) ? -R : ((((i - j + 1) & 1) ? -R : R));
        G[(size_t)i * W + j]     = (i == j ? 1.0 : 0.0) - 0.5 * dt * a;
        G[(size_t)i * W + N + j] = (i == j ? 1.0 : 0.0) + 0.5 * dt * a;
      }
      G[(size_t)i * W + N + 256] = dt * (((i & 1) ? -R : R));
    }
    for (int k = 0; k < N; ++k) {
      int piv = k; double best = fabs(G[(size_t)k * W + k]);
      for (int r = k + 1; r < N; ++r) {
        double v = fabs(G[(size_t)r * W + k]);
        if (v > best) { best = v; piv = r; }
      }
      if (piv != k)
        for (int c = k; c < W; ++c) std::swap(G[(size_t)k * W + c], G[(size_t)piv * W + c]);
      double inv = 1.0 / G[(size_t)k * W + k];
      for (int r = k + 1; r < N; ++r) {
        double f = G[(size_t)r * W + k] * inv;
        if (f != 0.0) {
          double* Rr = &G[(size_t)r * W];
          const double* Rk = &G[(size_t)k * W];
          for (int c = k; c < W; ++c) Rr[c] -= f * Rk[c];
        }
      }
    }
    std::vector<double> X((size_t)N * 257);
    for (int k = N - 1; k >= 0; --k) {
      double inv = 1.0 / G[(size_t)k * W + k];
      const double* Rk = &G[(size_t)k * W];
      for (int c = 0; c < 257; ++c) {
        double v = Rk[N + c];
        for (int j = k + 1; j < N; ++j) v -= Rk[j] * X[(size_t)j * 257 + c];
        X[(size_t)k * 257 + c] = v * inv;
      }
    }
    std::vector<double> Ad((size_t)N * N), kvec(N), knew(N);
    for (int i = 0; i < N; ++i)
      for (int j = 0; j < N; ++j)
        Ad[(size_t)i * N + j] = (double)(float)X[(size_t)i * 257 + j];
    for (int i = 0; i < N; ++i) kvec[i] = (double)(float)X[(size_t)i * 257 + 256];

    ushort_t* fkt = outu + 98304 * ((1 << s) - 1);
    for (int d = 0; d < L; ++d) {
      if (d > 0) {
        for (int i = 0; i < N; ++i) {
          const double* row = &Ad[(size_t)i * N];
          double acc = 0.0;
          for (int j = 0; j < N; ++j) acc += row[j] * kvec[j];
          knew[i] = acc;
        }
        kvec.swap(knew);
      }
      for (int n = 0; n < N; ++n) {
        float kv = (float)kvec[n];
        unsigned short hi = h_f2b(kv);
        unsigned short lo = h_f2b(kv - h_b2f(hi));
        size_t base = ((size_t)((d >> 5) * 16 + (n >> 4)) * 2) * 512
                    + (size_t)((d & 31) >> 3) * 128 + (size_t)(n & 15) * 8 + (d & 7);
        fkt[base]       = hi;
        fkt[base + 512] = lo;
      }
    }
  }
}

static bool  g_dev_ok  = false;
static void* g_dev_ptr = nullptr;

namespace {
struct ConstInit {
  ConstInit() {
    compute_consts_host(g_consts);
    void* p = nullptr;
    if (hipMalloc(&p, CONST_BYTES) == hipSuccess && p != nullptr) {
      if (hipMemcpy(p, g_consts, CONST_BYTES, hipMemcpyHostToDevice) == hipSuccess) {
        g_dev_ptr = p;
        g_dev_ok  = true;
      } else {
        (void)hipFree(p);
      }
    }
    (void)hipHostRegister((void*)g_consts, sizeof(g_consts), hipHostRegisterDefault);
  }
};
static ConstInit g_const_init;
}

// ---------------- device helpers ----------------
__device__ inline unsigned short f2b(float v) {
  unsigned int u = __float_as_uint(v);
  unsigned int r = (u + 0x7FFF + ((u >> 16) & 1)) >> 16;
  return (unsigned short)r;
}
__device__ inline float b2f(unsigned short h) {
  return __uint_as_float((unsigned int)h << 16);
}
__device__ inline unsigned int pack2(float a, float b) {
  return (unsigned int)f2b(a) | ((unsigned int)f2b(b) << 16);
}

__device__ inline float blockReduceSum(float v) {
  __shared__ float sm[4];
  #pragma unroll
  for (int off = 32; off > 0; off >>= 1) v += __shfl_down(v, off);
  int wid = threadIdx.x >> 6, lane = threadIdx.x & 63;
  if (lane == 0) sm[wid] = v;
  __syncthreads();
  if (threadIdx.x == 0) sm[0] = sm[0] + sm[1] + sm[2] + sm[3];
  __syncthreads();
  float r = sm[0];
  __syncthreads();
  return r;
}

// instance norm over SEQ, write transposed xcT[bj][t]
__global__ __launch_bounds__(256) void norm_kernel(
    const float* __restrict__ x_enc, const float* __restrict__ aw,
    const float* __restrict__ ab, float* __restrict__ xcT,
    float* __restrict__ means, float* __restrict__ stdev) {
  int bj = blockIdx.x; int b = bj / 21, j = bj % 21;
  const float* xp = x_enc + (size_t)b * 768 * 21 + j;
  int tid = threadIdx.x;
  float lv[3]; float s = 0.f;
  #pragma unroll
  for (int i = 0; i < 3; ++i) { lv[i] = xp[(size_t)(tid + 256 * i) * 21]; s += lv[i]; }
  float tot = blockReduceSum(s);
  float mean = tot * (1.0f / 768.0f);
  float v = 0.f;
  #pragma unroll
  for (int i = 0; i < 3; ++i) { float d = lv[i] - mean; v += d * d; }
  float totv = blockReduceSum(v);
  float sd = sqrtf(totv * (1.0f / 768.0f) + 1e-5f);
  if (tid == 0) { means[bj] = mean; stdev[bj] = sd; }
  float wj = aw[j], bjv = ab[j];
  #pragma unroll
  for (int i = 0; i < 3; ++i)
    xcT[(size_t)bj * 768 + tid + 256 * i] = ((lv[i] - mean) / sd) * wj + bjv;
}

// ---- batched chunked prefix-DFT (f32 rotators, f64 anchors + accum).
__global__ __launch_bounds__(256) void xp1_kernel(
    const float* __restrict__ xcT, double2* __restrict__ P) {
  int tid = blockIdx.x * 256 + threadIdx.x;
  if (tid >= 5376 * 42) return;
  int nk = tid % 5376, cg = tid / 5376;
  int scale = (cg < 6) ? 0 : (cg < 18 ? 1 : 2);
  int c = cg - 6 * ((1 << scale) - 1);
  int L = 192 << scale;
  int bj = nk >> 5, k = nk & 31;
  const float* x = xcT + (size_t)bj * 768 + (768 - L);
  int u0 = c * 32;
  double ang = -2.0 * PI_D * (double)((k * u0) % L) / (double)L;
  float re = (float)cos(ang), im = (float)sin(ang);
  double wang = -2.0 * PI_D * (double)k / (double)L;
  float cw = (float)cos(wang), sw = (float)sin(wang);
  double sre = 0.0, sim = 0.0;
  #pragma unroll 8
  for (int j = 0; j < 32; ++j) {
    float xv = x[u0 + j];
    sre += (double)(xv * re); sim += (double)(xv * im);
    float nr = re * cw - im * sw, ni = re * sw + im * cw;
    re = nr; im = ni;
  }
  P[(size_t)cg * 5376 + nk] = make_double2(sre, sim);
}

// Phase 2 (batched): scan + emit Y frag-linear bf16 hi/lo per scale.
__global__ __launch_bounds__(256) void xp2_kernel(
    const float* __restrict__ xcT, const double2* __restrict__ P,
    ushort_t* __restrict__ YF) {
  int tid = blockIdx.x * 256 + threadIdx.x;
  if (tid >= 5376 * 42) return;
  int nk = tid % 5376, cg = tid / 5376;
  int scale = (cg < 6) ? 0 : (cg < 18 ? 1 : 2);
  int cbase = 6 * ((1 << scale) - 1);
  int c = cg - cbase;
  int L = 192 << scale;
  ushort_t* FA = YF + (size_t)4128768 * ((1 << scale) - 1);
  int bj = nk >> 5, k = nk & 31;
  const float* x = xcT + (size_t)bj * 768 + (768 - L);
  double bre = 0.0, bim = 0.0;
  for (int cc = cbase; cc < cg; ++cc) {
    double2 p = P[(size_t)cc * 5376 + nk];
    bre += p.x; bim += p.y;
  }
  int u0 = c * 32;
  double ang = -2.0 * PI_D * (double)((k * u0) % L) / (double)L;
  float ure = (float)cos(ang), uim = (float)sin(ang);
  double wang = -2.0 * PI_D * (double)k / (double)L;
  float cw = (float)cos(wang), sw = (float)sin(wang);
  int d0 = L - 1 - u0;
  double angd = -2.0 * PI_D * (double)((k * d0) % L) / (double)L;
  float dre = (float)cos(angd), dim = (float)sin(angd);

  float vre_buf[32], vim_buf[32];
  #pragma unroll
  for (int j = 0; j < 32; ++j) {
    float xv = x[u0 + j];
    bre += (double)(xv * ure); bim += (double)(xv * uim);
    float brf = (float)bre, bif = (float)bim;
    int m = 31 - j;
    vre_buf[m] = dre * brf - dim * bif;
    vim_buf[m] = dre * bif + dim * brf;
    float t1 = ure * cw - uim * sw, t2 = ure * sw + uim * cw;
    ure = t1; uim = t2;                  // *= e^{-i w}
    float t3 = dre * cw + dim * sw, t4 = dim * cw - dre * sw;
    dre = t3; dim = t4;                  // *= e^{+i w}
  }

  int nK0 = L >> 5;
  int K0 = (d0 - 31) >> 5;
  int rre = bj * 64 + k * 2;
  int rim = rre + 1;
  size_t baseRe = (((size_t)(rre >> 4) * nK0 + K0) * 2) * 512 + (size_t)(rre & 15) * 8;
  size_t baseIm = (((size_t)(rim >> 4) * nK0 + K0) * 2) * 512 + (size_t)(rim & 15) * 8;
  #pragma unroll
  for (int q = 0; q < 4; ++q) {
    float f0 = vre_buf[q*8+0], f1 = vre_buf[q*8+1], f2 = vre_buf[q*8+2], f3 = vre_buf[q*8+3];
    float f4 = vre_buf[q*8+4], f5 = vre_buf[q*8+5], f6 = vre_buf[q*8+6], f7 = vre_buf[q*8+7];
    uint4 vh = make_uint4(pack2(f0,f1), pack2(f2,f3), pack2(f4,f5), pack2(f6,f7));
    uint4 vl = make_uint4(pack2(f0-b2f(f2b(f0)), f1-b2f(f2b(f1))),
                          pack2(f2-b2f(f2b(f2)), f3-b2f(f2b(f3))),
                          pack2(f4-b2f(f2b(f4)), f5-b2f(f2b(f5))),
                          pack2(f6-b2f(f2b(f6)), f7-b2f(f2b(f7))));
    *(uint4*)(FA + baseRe + q*128)       = vh;
    *(uint4*)(FA + baseRe + 512 + q*128) = vl;
  }
  #pragma unroll
  for (int q = 0; q < 4; ++q) {
    float f0 = vim_buf[q*8+0], f1 = vim_buf[q*8+1], f2 = vim_buf[q*8+2], f3 = vim_buf[q*8+3];
    float f4 = vim_buf[q*8+4], f5 = vim_buf[q*8+5], f6 = vim_buf[q*8+6], f7 = vim_buf[q*8+7];
    uint4 vh = make_uint4(pack2(f0,f1), pack2(f2,f3), pack2(f4,f5), pack2(f6,f7));
    uint4 vl = make_uint4(pack2(f0-b2f(f2b(f0)), f1-b2f(f2b(f1))),
                          pack2(f2-b2f(f2b(f2)), f3-b2f(f2b(f3))),
                          pack2(f4-b2f(f2b(f4)), f5-b2f(f2b(f5))),
                          pack2(f6-b2f(f2b(f6)), f7-b2f(f2b(f7))));
    *(uint4*)(FA + baseIm + q*128)       = vh;
    *(uint4*)(FA + baseIm + 512 + q*128) = vl;
  }
}

// FUSED wb + gemm1 v8 (measured best): blocks [0,384) wb; blocks [384,720)
// gemm1 with 2 M-strips per mh-wave (96-row tiles): 24 MFMA per 12-load set,
// depth-2 register pipeline, B traffic halved vs 672 blocks.
__global__ __launch_bounds__(768, 3) void gemm1_wb(
    const ushort_t* __restrict__ YF, const ushort_t* __restrict__ KTall,
    ushort_t* __restrict__ AHI, ushort_t* __restrict__ ALO,
    const float* __restrict__ wrS_all, const float* __restrict__ wiS_all,
    const float* __restrict__ trig_all, ushort_t* __restrict__ FB2_all) {
  if (blockIdx.x < 384) {
    // ---- wb path (512 active threads) ----
    if (threadIdx.x >= 512) return;
    int wbid = blockIdx.x;
    int of  = wbid & 15;
    int nsb = (wbid >> 4) & 7;
    int s   = wbid >> 7;
    const float* wrS = wrS_all + (size_t)s * 256 * 256 * 32;
    const float* wiS = wiS_all + (size_t)s * 256 * 256 * 32;
    const float* trig = trig_all + s * 64;
    ushort_t* FB2 = FB2_all + (size_t)s * 8388608;
    int L = 192 << s;
    int t = threadIdx.x;
    int lgk = t >> 7;
    int e   = t & 7;
    int om  = (t >> 3) & 15;
    int nstate = nsb * 32 + lgk * 8 + e;
    int o = of * 16 + om;
    const float* wrp = wrS + ((size_t)nstate * 256 + o) * 32;
    const float* wip = wiS + ((size_t)nstate * 256 + o) * 32;
    float invL = 1.0f / (float)L;
    #pragma unroll 4
    for (int k = 0; k < 32; ++k) {
      float ck = trig[2 * k], sk = trig[2 * k + 1];
      float fk = (k == 0 ? 1.0f : 2.0f) * invL;
      float wr = wrp[k], wi = wip[k];
      float vre = fk * (wr * ck - wi * sk);
      float vim = fk * (-wi * ck - wr * sk);
      int qre = (k * 2) * 8 + nsb;
      size_t bre = ((size_t)(qre * 16 + of) * 2) * 512 + t;
      size_t bim = ((size_t)((qre + 8) * 16 + of) * 2) * 512 + t;
      unsigned short hre = f2b(vre), him = f2b(vim);
      FB2[bre]       = hre;
      FB2[bre + 512] = f2b(vre - b2f(hre));
      FB2[bim]       = him;
      FB2[bim + 512] = f2b(vim - b2f(him));
    }
    return;
  }

  // ---- gemm1 path v8: 112x3 logical grid, 12 waves, 2 strips per mh ----
  const int gb = blockIdx.x - 384;
  const int s = gb / 112;
  const int bx = gb % 112;
  const int K = 192 << s;
  const ushort_t* FA = YF + (size_t)4128768 * ((1 << s) - 1);
  const ushort_t* FB = KTall + (size_t)98304 * ((1 << s) - 1);
  ushort_t* Chi = AHI + (size_t)2752512 * s;
  ushort_t* Clo = ALO + (size_t)2752512 * s;

  const int wave = threadIdx.x >> 6;
  const int lane = threadIdx.x & 63;
  const int li = lane & 15, lg = lane >> 4;
  const int mh = wave >> 2;             // 0..2
  const int nw = wave & 3;              // 0..3 col quarter
  const int bn = nw * 64;
  const int nK0 = K >> 5;               // 6, 12, 24 (even)
  const int strip = bx * 6 + mh * 2;    // this wave covers strip, strip+1
  const int nf0 = nw * 4;

  bf16x8 aH0[2], aL0[2], bH0[4], bL0[4];
  bf16x8 aH1[2], aL1[2], bH1[4], bL1[4];
  f32x4 acc[2][4] = {};

  #define G1_LOAD(AH, AL, BH, BL, K0_) {                                      \
    _Pragma("unroll")                                                         \
    for (int st = 0; st < 2; ++st) {                                          \
      size_t fa = ((size_t)((strip + st) * nK0 + (K0_)) * 2) * 512 + lane * 8;\
      AH[st] = *(const bf16x8*)(FA + fa);                                     \
      AL[st] = *(const bf16x8*)(FA + fa + 512);                               \
    }                                                                         \
    _Pragma("unroll")                                                         \
    for (int nf = 0; nf < 4; ++nf) {                                          \
      size_t fb = ((size_t)((K0_) * 16 + nf0 + nf) * 2) * 512 + lane * 8;     \
      BH[nf] = *(const bf16x8*)(FB + fb);                                     \
      BL[nf] = *(const bf16x8*)(FB + fb + 512);                               \
    } }

  #define G1_MFMA(AH, AL, BH, BL) {                                          \
    _Pragma("unroll")                                                        \
    for (int st = 0; st < 2; ++st)                                           \
      _Pragma("unroll")                                                      \
      for (int nf = 0; nf < 4; ++nf) {                                       \
        acc[st][nf] = __builtin_amdgcn_mfma_f32_16x16x32_bf16(AH[st], BH[nf], acc[st][nf], 0, 0, 0); \
        acc[st][nf] = __builtin_amdgcn_mfma_f32_16x16x32_bf16(AH[st], BL[nf], acc[st][nf], 0, 0, 0); \
        acc[st][nf] = __builtin_amdgcn_mfma_f32_16x16x32_bf16(AL[st], BH[nf], acc[st][nf], 0, 0, 0); \
      } }

  G1_LOAD(aH0, aL0, bH0, bL0, 0);
  for (int K0 = 0; K0 < nK0; K0 += 2) {
    G1_LOAD(aH1, aL1, bH1, bL1, K0 + 1);
    G1_MFMA(aH0, aL0, bH0, bL0);
    if (K0 + 2 < nK0) G1_LOAD(aH0, aL0, bH0, bL0, K0 + 2);
    G1_MFMA(aH1, aL1, bH1, bL1);
  }
  #undef G1_LOAD
  #undef G1_MFMA

  #pragma unroll
  for (int st = 0; st < 2; ++st) {
    #pragma unroll
    for (int r = 0; r < 4; ++r) {
      int row = (strip + st) * 16 + lg * 4 + r;
      #pragma unroll
      for (int nf = 0; nf < 4; ++nf) {
        int col = bn + nf * 16 + li;
        float v = acc[st][nf][r];
        unsigned short hi = f2b(v);
        Chi[(size_t)row * 256 + col] = hi;
        Clo[(size_t)row * 256 + col] = f2b(v - b2f(hi));
      }
    }
  }
}

// GEMM2 (batched): grid (4 nx, 3 my, 96 = scale*32+z), 256 thr.
__global__ __launch_bounds__(256) void gemm2_mfma(
    const ushort_t* __restrict__ AHI, const ushort_t* __restrict__ ALO,
    const ushort_t* __restrict__ FB2_all, float* __restrict__ PART) {
  const int zz = blockIdx.z;
  const int s = zz >> 5;
  const int z = zz & 31;
  const ushort_t* Ahi = AHI + (size_t)2752512 * s;
  const ushort_t* Alo = ALO + (size_t)2752512 * s;
  const ushort_t* FB2 = FB2_all + (size_t)s * 8388608;
  float* C = PART + (size_t)s * 1376256 + (size_t)z * 43008;

  const int wave = threadIdx.x >> 6;
  const int lane = threadIdx.x & 63;
  const int li = lane & 15, lg = lane >> 4;
  const int bm = blockIdx.y * 64;
  const int bn = blockIdx.x * 64;
  const int nf0 = blockIdx.x * 4;
  const int ks = z * 512;

  const int rowA = bm + wave * 16 + li;
  const bool aok = (rowA < 168);
  const size_t aoff = (size_t)(aok ? rowA : 0) * 16384;

  bf16x8 aH0, aL0, bH0[4], bL0[4];
  bf16x8 aH1, aL1, bH1[4], bL1[4];
  f32x4 acc[4] = {};

  #define G2_LOAD(AH, AL, BH, BL, KC_) {                                   \
    int kc_ = (KC_) + lg * 8;                                              \
    if (aok) { AH = *(const bf16x8*)(Ahi + aoff + kc_);                    \
               AL = *(const bf16x8*)(Alo + aoff + kc_); }                  \
    else     { AH = (bf16x8)(short)0; AL = (bf16x8)(short)0; }             \
    int q_ = (KC_) >> 5;                                                   \
    _Pragma("unroll")                                                      \
    for (int nf = 0; nf < 4; ++nf) {                                       \
      size_t fb = ((size_t)(q_ * 16 + nf0 + nf) * 2) * 512 + lane * 8;     \
      BH[nf] = *(const bf16x8*)(FB2 + fb);                                 \
      BL[nf] = *(const bf16x8*)(FB2 + fb + 512);                           \
    } }

  #define G2_MFMA(AH, AL, BH, BL) {                                        \
    _Pragma("unroll")                                                      \
    for (int nf = 0; nf < 4; ++nf) {                                       \
      acc[nf] = __builtin_amdgcn_mfma_f32_16x16x32_bf16(AH, BH[nf], acc[nf], 0, 0, 0); \
      acc[nf] = __builtin_amdgcn_mfma_f32_16x16x32_bf16(AH, BL[nf], acc[nf], 0, 0, 0); \
      acc[nf] = __builtin_amdgcn_mfma_f32_16x16x32_bf16(AL, BH[nf], acc[nf], 0, 0, 0); \
    } }

  G2_LOAD(aH0, aL0, bH0, bL0, ks);
  for (int k0 = ks; k0 < ks + 512; k0 += 64) {
    G2_LOAD(aH1, aL1, bH1, bL1, k0 + 32);
    G2_MFMA(aH0, aL0, bH0, bL0);
    if (k0 + 64 < ks + 512) G2_LOAD(aH0, aL0, bH0, bL0, k0 + 64);
    G2_MFMA(aH1, aL1, bH1, bL1);
  }
  #undef G2_LOAD
  #undef G2_MFMA

  #pragma unroll
  for (int r = 0; r < 4; ++r) {
    int row = bm + wave * 16 + lg * 4 + r;
    if (row < 168) {
      #pragma unroll
      for (int nf = 0; nf < 4; ++nf) {
        int col = bn + nf * 16 + li;
        C[(size_t)row * 256 + col] = acc[nf][r];
      }
    }
  }
}

// reduce (batched): grid (168, 3)
__global__ __launch_bounds__(256) void reduce_kernel(
    const float* __restrict__ PART, float* __restrict__ OUT1) {
  int s = blockIdx.y;
  int e = blockIdx.x * 256 + threadIdx.x;   // 43008 exact
  const float* part = PART + (size_t)s * 1376256;
  float sum = 0.f;
  for (int c = 0; c < 32; ++c) sum += part[(size_t)c * 43008 + e];
  OUT1[(size_t)s * 43008 + e] = sum;
}

// out[b][p][j] = ((sum_s mlpw_s*(out1_s[bj].evp_s[p]) + mlpb) - ab[j])/(aw[j]+1e-10)*sd + mean
__global__ __launch_bounds__(256) void final_kernel(
    const float* __restrict__ out1, const float* __restrict__ evp,
    const float* __restrict__ means, const float* __restrict__ stdev,
    const float* __restrict__ aw, const float* __restrict__ ab,
    const float* __restrict__ mlp_w, const float* __restrict__ mlp_b,
    float* __restrict__ out) {
  int tid = blockIdx.x * 256 + threadIdx.x;   // 8*192*21 = 32256 exact
  int j = tid % 21; int bp = tid / 21; int p = bp % 192; int b = bp / 192;
  int bj = b * 21 + j;
  float acc = mlp_b[0];
  #pragma unroll
  for (int s = 0; s < 3; ++s) {
    const float* o1 = out1 + ((size_t)s * 168 + bj) * 256;
    const float* ev = evp + ((size_t)s * 192 + p) * 256;
    float d = 0.f;
    #pragma unroll 4
    for (int n = 0; n < 256; ++n) d = fmaf(o1[n], ev[n], d);
    acc = fmaf(mlp_w[s], d, acc);
  }
  float v = (acc - ab[j]) / (aw[j] + 1e-10f);
  out[tid] = v * stdev[bj] + means[bj];
}

// ---------------- launch ----------------
extern "C" void kernel_launch(void* const* d_in, const int* in_sizes, int n_in,
                              void* d_out, int out_size, void* d_ws, size_t ws_size,
                              hipStream_t stream) {
  const float* x_enc   = (const float*)d_in[0];
  const float* aw      = (const float*)d_in[4];
  const float* ab      = (const float*)d_in[5];
  const float* spec_wr = (const float*)d_in[6];
  const float* spec_wi = (const float*)d_in[7];
  const float* mlp_w   = (const float*)d_in[8];
  const float* mlp_b   = (const float*)d_in[9];
  float* wsf = (float*)d_ws;
  float* out = (float*)d_out;

  const unsigned char* cst_base;
  if (g_dev_ok) {
    cst_base = (const unsigned char*)g_dev_ptr;   // uploaded once at dlopen
  } else {
    hipMemcpyAsync(wsf + OFF_CFALL, g_consts, CONST_BYTES,
                   hipMemcpyHostToDevice, stream);
    cst_base = (const unsigned char*)(wsf + OFF_CFALL);
  }
  const float*    cst_f  = (const float*)cst_base;
  const ushort_t* cst_us = (const ushort_t*)(cst_base + CF_FLOATS * 4);

  ushort_t* yf  = (ushort_t*)(wsf + OFF_YF);
  ushort_t* ahi = (ushort_t*)(wsf + OFF_AHI);
  ushort_t* alo = (ushort_t*)(wsf + OFF_ALO);
  ushort_t* fb2 = (ushort_t*)(wsf + OFF_FB2);

  norm_kernel<<<168, 256, 0, stream>>>(x_enc, aw, ab,
      wsf + OFF_XCT, wsf + OFF_MEANS, wsf + OFF_STD);

  // batched over all 3 scales:
  xp1_kernel<<<(5376 * 42 + 255) / 256, 256, 0, stream>>>(
      wsf + OFF_XCT, (double2*)(wsf + OFF_XP1P));
  xp2_kernel<<<(5376 * 42 + 255) / 256, 256, 0, stream>>>(
      wsf + OFF_XCT, (const double2*)(wsf + OFF_XP1P), yf);
  // fused wb (384 blocks) + gemm1 v8 (336 blocks, 96-row tiles)
  gemm1_wb<<<384 + 336, 768, 0, stream>>>(
      yf, cst_us, ahi, alo,
      spec_wr, spec_wi, cst_f + CF_TRIG_F, fb2);
  gemm2_mfma<<<dim3(4, 3, 96), 256, 0, stream>>>(
      ahi, alo, fb2, wsf + OFF_PART);
  reduce_kernel<<<dim3(168, 3), 256, 0, stream>>>(
      wsf + OFF_PART, wsf + OFF_OUT1);

  final_kernel<<<126, 256, 0, stream>>>(
      wsf + OFF_OUT1, cst_f + CF_EVP_F, wsf + OFF_MEANS, wsf + OFF_STD,
      aw, ab, mlp_w, mlp_b, out);
}